// Round 1
// baseline (114.337 us; speedup 1.0000x reference)
//
#include <hip/hip_runtime.h>

typedef short short4v __attribute__((ext_vector_type(4)));
typedef short short8v __attribute__((ext_vector_type(8)));
typedef float float4v __attribute__((ext_vector_type(4)));
typedef unsigned short u16;

#define NB 2
#define NL 2048
#define NS 2048
#define NH 8
#define NE 64
#define HE (NH*NE)    // 512
#define NLT (NL/64)   // 32 l-tiles per (b,h)
#define NST (NS/64)   // 32 s-tiles
#define TILE_U16 4096 // one 64x64 bf16 tile image = 8 KB

// pack two fp32 -> dword of two bf16 (round-to-nearest, half-up)
static __device__ __forceinline__ unsigned pk2bf(float a, float b) {
  union { float f; unsigned u; } x, y; x.f = a; y.f = b;
  return __builtin_amdgcn_perm(y.u + 0x8000u, x.u + 0x8000u, 0x07060302u);
}

#define GLD16(gp, lp) __builtin_amdgcn_global_load_lds( \
    (const __attribute__((address_space(1))) void*)(gp), \
    (__attribute__((address_space(3))) void*)(lp), 16, 0, 0)

// K-image swizzle hash: uses s bits {0,1,3} so the permuted QK row set
// (s = 8*(ln15>>2) + (ln15&3) + 4c) still spans all 8 chunk slots.
static __device__ __forceinline__ int fK(int s) { return (s & 3) | ((s >> 1) & 4); }

// ---------------------------------------------------------------------------
// Pre-pass: K,V fp32 -> bf16 tile images in d_ws, in the EXACT swizzled byte
// order the main kernel's LDS wants (K row-major, V transposed). K and V in
// separate blocks (1024 WGs, 4/CU) for latency overlap.
// ---------------------------------------------------------------------------
__global__ __launch_bounds__(256)
void prepack(const float* __restrict__ kp, const float* __restrict__ vp,
             u16* __restrict__ kimg, u16* __restrict__ vimg)
{
  __shared__ __align__(16) u16 ldsv[TILE_U16];

  const int bid  = blockIdx.x;          // 0..1023
  const int tile = bid >> 1;            // bh*NST + st
  const int doV  = bid & 1;
  const int st = tile & (NST - 1);
  const int bh = tile >> 5;
  const int h  = bh & (NH - 1);
  const int b  = bh >> 3;
  const int s0 = st * 64;
  const size_t base = (size_t)b * NS * HE + h * NE;
  const int tid  = threadIdx.x;
  const int wv   = tid >> 6;
  const int lane = tid & 63;
  const int ln7  = lane & 7;

  if (!doV) {
    u16* kt = kimg + (size_t)tile * TILE_U16;
    for (int slot = tid; slot < 512; slot += 256) {
      const int srow = slot >> 3, p = slot & 7, c = p ^ fK(srow);
      const float* src = kp + base + (size_t)(s0 + srow) * HE + c * 8;
      float4 x0 = *(const float4*)src;
      float4 x1 = *(const float4*)(src + 4);
      unsigned d[4] = { pk2bf(x0.x, x0.y), pk2bf(x0.z, x0.w),
                        pk2bf(x1.x, x1.y), pk2bf(x1.z, x1.w) };
      *(int4*)(kt + slot * 8) = *(const int4*)d;
    }
    return;
  }

  u16* vt = vimg + (size_t)tile * TILE_U16;
  {
    const float* vcol = vp + base + (size_t)(s0 + wv * 16) * HE + lane;
    unsigned vr[8];
    #pragma unroll
    for (int jj = 0; jj < 8; ++jj)
      vr[jj] = pk2bf(vcol[(size_t)(2 * jj) * HE], vcol[(size_t)(2 * jj + 1) * HE]);
    #pragma unroll
    for (int i = 0; i < 2; ++i) {
      const int cs = (2 * wv + i) ^ ln7;
      int4 t4 = make_int4((int)vr[4*i+0], (int)vr[4*i+1],
                          (int)vr[4*i+2], (int)vr[4*i+3]);
      *(int4*)(&ldsv[lane * 64 + cs * 8]) = t4;
    }
  }
  __syncthreads();
  {
    const int4* s = (const int4*)ldsv;
    int4* dst = (int4*)vt;
    dst[tid]       = s[tid];
    dst[tid + 256] = s[tid + 256];
  }
}

// ---------------------------------------------------------------------------
// Main: one 256-thr WG = (b,h, 64-row l-tile), full S sweep.
// NEW (this round, T3+T4+T5 bundle):
//   - 4 LDS buffers (64 KB/block, 2 blocks/CU), prefetch depth 3 tiles
//   - counted s_waitcnt vmcnt(8) per tile (never a full drain in steady
//     state) + raw s_barrier instead of s_waitcnt(0)+__syncthreads
//   - s_setprio(1) around the QK and PV MFMA clusters
// Math unchanged: row-permuted K=32 QK -> in-register relu^2/exp -> K=32 PV,
// softmax denominator via ones-B MFMA on the matrix pipe.
// ---------------------------------------------------------------------------
__global__ __launch_bounds__(256, 2)
void assa_fwd(const float* __restrict__ qp, const u16* __restrict__ kimg,
              const u16* __restrict__ vimg, const float* __restrict__ a1p,
              const float* __restrict__ a2p, float* __restrict__ op)
{
  __shared__ __align__(16) u16 ldsb[4][2 * TILE_U16];  // [buf][K | V] = 64 KB

  const int tid  = threadIdx.x;
  const int wv   = tid >> 6;
  const int lane = tid & 63;
  const int ln15 = lane & 15;
  const int ln7  = lane & 7;
  const int quad = lane >> 4;

  // XCD swizzle: all 32 l-tiles of one (b,h) on one XCD
  const int bid = blockIdx.x;
  const int bh  = bid & 15;
  const int lt  = bid >> 4;
  const int h   = bh & (NH - 1);
  const int b   = bh >> 3;

  const int lbase = lt * 64 + wv * 16;

  // Q B-fragments, pre-scaled by 1/sqrt(64) (exact exponent shift)
  short8v qf0, qf1;
  {
    const float* qrow = qp + ((size_t)(b * NL + lbase + ln15)) * HE + h * NE + quad * 8;
    float4 q0 = *(const float4*)(qrow);
    float4 q1 = *(const float4*)(qrow + 4);
    float4 q2 = *(const float4*)(qrow + 32);
    float4 q3 = *(const float4*)(qrow + 36);
    unsigned d0[4] = { pk2bf(0.125f*q0.x, 0.125f*q0.y), pk2bf(0.125f*q0.z, 0.125f*q0.w),
                       pk2bf(0.125f*q1.x, 0.125f*q1.y), pk2bf(0.125f*q1.z, 0.125f*q1.w) };
    unsigned d1[4] = { pk2bf(0.125f*q2.x, 0.125f*q2.y), pk2bf(0.125f*q2.z, 0.125f*q2.w),
                       pk2bf(0.125f*q3.x, 0.125f*q3.y), pk2bf(0.125f*q3.z, 0.125f*q3.w) };
    qf0 = *(const short8v*)d0;
    qf1 = *(const short8v*)d1;
  }

  // ones B-fragment (bf16 1.0 in every slot) for the denominator MFMA
  short8v ones8;
  #pragma unroll
  for (int j = 0; j < 8; ++j) ones8[j] = (short)0x3F80;

  const size_t tbase = (size_t)bh * NST;

  float4v acc_s[4], acc_d[4], acc_l;
  #pragma unroll
  for (int t = 0; t < 4; ++t)
    #pragma unroll
    for (int r = 0; r < 4; ++r) { acc_s[t][r] = 0.0f; acc_d[t][r] = 0.0f; }
  #pragma unroll
  for (int r = 0; r < 4; ++r) acc_l[r] = 0.0f;

  // DMA one tile (16 KB) into buffer nb: waves 0,1 -> K image, waves 2,3 -> V.
  // 4 global_load_lds per wave per tile (vmcnt accounting relies on this).
  auto dma_tile = [&](int st, int nb) {
    const int hf = wv & 1;
    const u16* g;
    u16* l;
    if (wv < 2) {
      g = kimg + (tbase + st) * TILE_U16 + hf * 2048 + lane * 8;
      l = &ldsb[nb][hf * 2048];
    } else {
      g = vimg + (tbase + st) * TILE_U16 + hf * 2048 + lane * 8;
      l = &ldsb[nb][TILE_U16 + hf * 2048];
    }
    GLD16(g,        l);
    GLD16(g +  512, l +  512);
    GLD16(g + 1024, l + 1024);
    GLD16(g + 1536, l + 1536);
  };

  // prologue: 3 tiles in flight (12 outstanding loads per wave)
  dma_tile(0, 0);
  dma_tile(1, 1);
  dma_tile(2, 2);

  const int rperm = 8 * (ln15 >> 2) + (ln15 & 3);          // + 32U + 4c
  const int fk    = (ln15 & 3) | (((ln15 >> 2) & 1) << 2); // fK of that row

  for (int st = 0; st < NST; ++st) {
    // counted wait: oldest in-flight tile (st) complete; loads for tiles
    // st+1..st+2 (8 per wave) stay in flight across the barrier.
    if (st + 2 < NST)      asm volatile("s_waitcnt vmcnt(8)" ::: "memory");
    else if (st + 1 < NST) asm volatile("s_waitcnt vmcnt(4)" ::: "memory");
    else                   asm volatile("s_waitcnt vmcnt(0)" ::: "memory");
    __builtin_amdgcn_s_barrier();
    asm volatile("" ::: "memory");  // keep DMA issue / LDS reads below barrier
    if (st + 3 < NST) dma_tile(st + 3, (st + 3) & 3);

    const u16* kb_l = ldsb[st & 3];
    const u16* vb_l = ldsb[st & 3] + TILE_U16;

    #pragma unroll
    for (int U = 0; U < 2; ++U) {
      float4v sa0, sa1;
      #pragma unroll
      for (int r = 0; r < 4; ++r) { sa0[r] = 0.0f; sa1[r] = 0.0f; }
      const u16* krow0 = &kb_l[(32 * U + rperm) * 64];
      const u16* krow1 = krow0 + 4 * 64;
      short8v kf00 = *(const short8v*)(krow0 + (quad ^ fk) * 8);
      short8v kf01 = *(const short8v*)(krow0 + ((4 + quad) ^ fk) * 8);
      short8v kf10 = *(const short8v*)(krow1 + (quad ^ fk) * 8);
      short8v kf11 = *(const short8v*)(krow1 + ((4 + quad) ^ fk) * 8);
      __builtin_amdgcn_s_setprio(1);
      sa0 = __builtin_amdgcn_mfma_f32_16x16x32_bf16(kf00, qf0, sa0, 0, 0, 0);
      sa0 = __builtin_amdgcn_mfma_f32_16x16x32_bf16(kf01, qf1, sa0, 0, 0, 0);
      sa1 = __builtin_amdgcn_mfma_f32_16x16x32_bf16(kf10, qf0, sa1, 0, 0, 0);
      sa1 = __builtin_amdgcn_mfma_f32_16x16x32_bf16(kf11, qf1, sa1, 0, 0, 0);
      __builtin_amdgcn_s_setprio(0);
      // lane (quad,l=ln15): sa0[r] = score[s=32U+8q+r][l], sa1[r] = +4

      float ps[8], pd[8];
      #pragma unroll
      for (int r = 0; r < 4; ++r) {
        float s0 = sa0[r], s1 = sa1[r];
        float r0 = s0 > 0.0f ? s0 : 0.0f;
        float r1 = s1 > 0.0f ? s1 : 0.0f;
        ps[r] = r0 * r0;  ps[4 + r] = r1 * r1;
        pd[r] = __expf(s0); pd[4 + r] = __expf(s1);
      }
      unsigned da[4] = { pk2bf(ps[0], ps[1]), pk2bf(ps[2], ps[3]),
                         pk2bf(ps[4], ps[5]), pk2bf(ps[6], ps[7]) };
      unsigned db[4] = { pk2bf(pd[0], pd[1]), pk2bf(pd[2], pd[3]),
                         pk2bf(pd[4], pd[5]), pk2bf(pd[6], pd[7]) };
      short8v as8 = *(const short8v*)da;   // A[m=l][k=s-32U] for K=32 PV
      short8v ad8 = *(const short8v*)db;

      __builtin_amdgcn_s_setprio(1);
      // denominator on the matrix pipe: acc_l[r] += sum_s pd[row=quad*4+r][s]
      acc_l = __builtin_amdgcn_mfma_f32_16x16x32_bf16(ad8, ones8, acc_l, 0, 0, 0);

      #pragma unroll
      for (int t = 0; t < 4; ++t) {
        short8v vf = *(const short8v*)(&vb_l[(t * 16 + ln15) * 64 +
                        (((4 * U + quad) ^ ln7) * 8)]);
        acc_s[t] = __builtin_amdgcn_mfma_f32_16x16x32_bf16(as8, vf, acc_s[t], 0, 0, 0);
        acc_d[t] = __builtin_amdgcn_mfma_f32_16x16x32_bf16(ad8, vf, acc_d[t], 0, 0, 0);
      }
      __builtin_amdgcn_s_setprio(0);
    }
  }

  const float w1 = __expf(a1p[0]), w2 = __expf(a2p[0]);
  const float al1 = w1 / (w1 + w2);
  const float al2 = w2 / (w1 + w2);

  // acc_l[r] is the full denominator for row quad*4+r (identical across cols)
  float c_d[4];
  #pragma unroll
  for (int r = 0; r < 4; ++r) c_d[r] = al2 / acc_l[r];

  #pragma unroll
  for (int t = 0; t < 4; ++t) {
    #pragma unroll
    for (int r = 0; r < 4; ++r) {
      float val = al1 * acc_s[t][r] + c_d[r] * acc_d[t][r];
      const int l = lbase + quad * 4 + r;
      const int e = t * 16 + ln15;
      op[((size_t)(b * NL + l)) * HE + h * NE + e] = val;
    }
  }
}

extern "C" void kernel_launch(void* const* d_in, const int* in_sizes, int n_in,
                              void* d_out, int out_size, void* d_ws, size_t ws_size,
                              hipStream_t stream) {
  const float* q  = (const float*)d_in[0];
  const float* k  = (const float*)d_in[1];
  const float* v  = (const float*)d_in[2];
  const float* a1 = (const float*)d_in[3];
  const float* a2 = (const float*)d_in[4];
  float* out = (float*)d_out;
  (void)in_sizes; (void)n_in; (void)out_size; (void)ws_size;

  u16* kimg = (u16*)d_ws;                                   // 4 MiB
  u16* vimg = kimg + (size_t)NB * NH * NST * TILE_U16;      // 4 MiB

  prepack<<<dim3(NB * NH * NST * 2), dim3(256), 0, stream>>>(k, v, kimg, vimg);
  assa_fwd<<<dim3(NB * NH * NLT), dim3(256), 0, stream>>>(q, kimg, vimg, a1, a2, out);
}

// Round 2
// 110.339 us; speedup vs baseline: 1.0362x; 1.0362x over previous
//
#include <hip/hip_runtime.h>

typedef short short4v __attribute__((ext_vector_type(4)));
typedef short short8v __attribute__((ext_vector_type(8)));
typedef float float4v __attribute__((ext_vector_type(4)));
typedef unsigned short u16;

#define NB 2
#define NL 2048
#define NS 2048
#define NH 8
#define NE 64
#define HE (NH*NE)    // 512
#define NLT (NL/64)   // 32 l-tiles per (b,h)
#define NST (NS/64)   // 32 s-tiles
#define TILE_U16 4096 // one 64x64 bf16 tile image = 8 KB

// pack two fp32 -> dword of two bf16 (round-to-nearest, half-up)
static __device__ __forceinline__ unsigned pk2bf(float a, float b) {
  union { float f; unsigned u; } x, y; x.f = a; y.f = b;
  return __builtin_amdgcn_perm(y.u + 0x8000u, x.u + 0x8000u, 0x07060302u);
}

// single-instruction pack: low16 = bf16(a), high16 = bf16(b), RTNE
static __device__ __forceinline__ unsigned cvtpk(float a, float b) {
  unsigned r;
  asm("v_cvt_pk_bf16_f32 %0, %1, %2" : "=v"(r) : "v"(a), "v"(b));
  return r;
}

// single-instruction 2^x
static __device__ __forceinline__ float fexp2(float x) {
  float r;
  asm("v_exp_f32 %0, %1" : "=v"(r) : "v"(x));
  return r;
}

#define GLD16(gp, lp) __builtin_amdgcn_global_load_lds( \
    (const __attribute__((address_space(1))) void*)(gp), \
    (__attribute__((address_space(3))) void*)(lp), 16, 0, 0)

// K-image swizzle hash: uses s bits {0,1,3} so the permuted QK row set
// (s = 8*(ln15>>2) + (ln15&3) + 4c) still spans all 8 chunk slots.
static __device__ __forceinline__ int fK(int s) { return (s & 3) | ((s >> 1) & 4); }

// ---------------------------------------------------------------------------
// Pre-pass: K,V fp32 -> bf16 tile images in d_ws, in the EXACT swizzled byte
// order the main kernel's LDS wants (K row-major, V transposed). K and V in
// separate blocks (1024 WGs, 4/CU) for latency overlap.
// ---------------------------------------------------------------------------
__global__ __launch_bounds__(256)
void prepack(const float* __restrict__ kp, const float* __restrict__ vp,
             u16* __restrict__ kimg, u16* __restrict__ vimg)
{
  __shared__ __align__(16) u16 ldsv[TILE_U16];

  const int bid  = blockIdx.x;          // 0..1023
  const int tile = bid >> 1;            // bh*NST + st
  const int doV  = bid & 1;
  const int st = tile & (NST - 1);
  const int bh = tile >> 5;
  const int h  = bh & (NH - 1);
  const int b  = bh >> 3;
  const int s0 = st * 64;
  const size_t base = (size_t)b * NS * HE + h * NE;
  const int tid  = threadIdx.x;
  const int wv   = tid >> 6;
  const int lane = tid & 63;
  const int ln7  = lane & 7;

  if (!doV) {
    u16* kt = kimg + (size_t)tile * TILE_U16;
    for (int slot = tid; slot < 512; slot += 256) {
      const int srow = slot >> 3, p = slot & 7, c = p ^ fK(srow);
      const float* src = kp + base + (size_t)(s0 + srow) * HE + c * 8;
      float4 x0 = *(const float4*)src;
      float4 x1 = *(const float4*)(src + 4);
      unsigned d[4] = { pk2bf(x0.x, x0.y), pk2bf(x0.z, x0.w),
                        pk2bf(x1.x, x1.y), pk2bf(x1.z, x1.w) };
      *(int4*)(kt + slot * 8) = *(const int4*)d;
    }
    return;
  }

  u16* vt = vimg + (size_t)tile * TILE_U16;
  {
    const float* vcol = vp + base + (size_t)(s0 + wv * 16) * HE + lane;
    unsigned vr[8];
    #pragma unroll
    for (int jj = 0; jj < 8; ++jj)
      vr[jj] = pk2bf(vcol[(size_t)(2 * jj) * HE], vcol[(size_t)(2 * jj + 1) * HE]);
    #pragma unroll
    for (int i = 0; i < 2; ++i) {
      const int cs = (2 * wv + i) ^ ln7;
      int4 t4 = make_int4((int)vr[4*i+0], (int)vr[4*i+1],
                          (int)vr[4*i+2], (int)vr[4*i+3]);
      *(int4*)(&ldsv[lane * 64 + cs * 8]) = t4;
    }
  }
  __syncthreads();
  {
    const int4* s = (const int4*)ldsv;
    int4* dst = (int4*)vt;
    dst[tid]       = s[tid];
    dst[tid + 256] = s[tid + 256];
  }
}

// ---------------------------------------------------------------------------
// Main. NEW this round: in-block S-split to double occupancy.
//   - 512-thread WG (8 waves), grid unchanged (512 WGs = 2/CU): waves 0-3
//     sweep EVEN s-tiles, waves 4-7 sweep ODD s-tiles -> 16 waves/CU
//     (4 waves/SIMD, 2x previous) to hide the QK->exp->PV serial chain.
//   - per-stream double-buffered LDS: [stream][buf][K|V] = 64 KB/block.
//   - partial acc (incl. softmax denominator, which is linear) combined
//     once at the end via LDS, column-major scalar layout (conflict-free).
//   - VALU cuts: Q pre-scaled by 0.125*log2(e) -> dense branch is a bare
//     v_exp_f32 (exp2); relu^2 branch is degree-2 homogeneous so the
//     (log2 e)^2 factor folds into alpha1 at the epilogue. P-matrix bf16
//     packs use 1-op v_cvt_pk_bf16_f32 instead of 3-op pk2bf.
// ---------------------------------------------------------------------------
__global__ __launch_bounds__(512, 4)
void assa_fwd(const float* __restrict__ qp, const u16* __restrict__ kimg,
              const u16* __restrict__ vimg, const float* __restrict__ a1p,
              const float* __restrict__ a2p, float* __restrict__ op)
{
  __shared__ __align__(16) u16 ldsb[2][2][2 * TILE_U16];  // [strm][buf][K|V] 64KB

  const int tid  = threadIdx.x;
  const int wv   = tid >> 6;        // 0..7
  const int ws   = wv & 3;          // l-group / dma role within stream
  const int strm = wv >> 2;         // 0: even s-tiles, 1: odd s-tiles
  const int lane = tid & 63;
  const int ln15 = lane & 15;
  const int ln7  = lane & 7;
  const int quad = lane >> 4;

  // XCD swizzle: all 32 l-tiles of one (b,h) on one XCD
  const int bid = blockIdx.x;
  const int bh  = bid & 15;
  const int lt  = bid >> 4;
  const int h   = bh & (NH - 1);
  const int b   = bh >> 3;

  const int lbase = lt * 64 + ws * 16;

  // Q B-fragments, pre-scaled by (1/sqrt(64)) * log2(e) so the dense branch
  // can use exp2 directly.
  short8v qf0, qf1;
  {
    const float qs = 0.125f * 1.44269504089f;
    const float* qrow = qp + ((size_t)(b * NL + lbase + ln15)) * HE + h * NE + quad * 8;
    float4 q0 = *(const float4*)(qrow);
    float4 q1 = *(const float4*)(qrow + 4);
    float4 q2 = *(const float4*)(qrow + 32);
    float4 q3 = *(const float4*)(qrow + 36);
    unsigned d0[4] = { pk2bf(qs*q0.x, qs*q0.y), pk2bf(qs*q0.z, qs*q0.w),
                       pk2bf(qs*q1.x, qs*q1.y), pk2bf(qs*q1.z, qs*q1.w) };
    unsigned d1[4] = { pk2bf(qs*q2.x, qs*q2.y), pk2bf(qs*q2.z, qs*q2.w),
                       pk2bf(qs*q3.x, qs*q3.y), pk2bf(qs*q3.z, qs*q3.w) };
    qf0 = *(const short8v*)d0;
    qf1 = *(const short8v*)d1;
  }

  // ones B-fragment (bf16 1.0 in every slot) for the denominator MFMA
  short8v ones8;
  #pragma unroll
  for (int j = 0; j < 8; ++j) ones8[j] = (short)0x3F80;

  const size_t tbase = (size_t)bh * NST;

  float4v acc_s[4], acc_d[4], acc_l;
  #pragma unroll
  for (int t = 0; t < 4; ++t)
    #pragma unroll
    for (int r = 0; r < 4; ++r) { acc_s[t][r] = 0.0f; acc_d[t][r] = 0.0f; }
  #pragma unroll
  for (int r = 0; r < 4; ++r) acc_l[r] = 0.0f;

  // DMA one tile (16 KB) into this stream's buffer nb:
  // ws 0,1 -> K image halves, ws 2,3 -> V. 4 global_load_lds per wave.
  auto dma_tile = [&](int st, int nb) {
    const int hf = ws & 1;
    const u16* g;
    u16* l;
    if (ws < 2) {
      g = kimg + (tbase + st) * TILE_U16 + hf * 2048 + lane * 8;
      l = &ldsb[strm][nb][hf * 2048];
    } else {
      g = vimg + (tbase + st) * TILE_U16 + hf * 2048 + lane * 8;
      l = &ldsb[strm][nb][TILE_U16 + hf * 2048];
    }
    GLD16(g,        l);
    GLD16(g +  512, l +  512);
    GLD16(g + 1024, l + 1024);
    GLD16(g + 1536, l + 1536);
  };

  dma_tile(strm, 0);   // stream's first tile (st = strm)

  const int rperm = 8 * (ln15 >> 2) + (ln15 & 3);          // + 32U + 4c
  const int fk    = (ln15 & 3) | (((ln15 >> 2) & 1) << 2); // fK of that row

  for (int it = 0; it < NST / 2; ++it) {
    // own loads drained BEFORE the barrier -> after it, everyone's data is in
    asm volatile("s_waitcnt vmcnt(0)" ::: "memory");
    __builtin_amdgcn_s_barrier();
    asm volatile("" ::: "memory");  // keep DMA issue / LDS reads below barrier
    if (it + 1 < NST / 2) dma_tile(2 * (it + 1) + strm, (it + 1) & 1);

    const u16* kb_l = ldsb[strm][it & 1];
    const u16* vb_l = kb_l + TILE_U16;

    #pragma unroll
    for (int U = 0; U < 2; ++U) {
      float4v sa0, sa1;
      #pragma unroll
      for (int r = 0; r < 4; ++r) { sa0[r] = 0.0f; sa1[r] = 0.0f; }
      const u16* krow0 = &kb_l[(32 * U + rperm) * 64];
      const u16* krow1 = krow0 + 4 * 64;
      short8v kf00 = *(const short8v*)(krow0 + (quad ^ fk) * 8);
      short8v kf01 = *(const short8v*)(krow0 + ((4 + quad) ^ fk) * 8);
      short8v kf10 = *(const short8v*)(krow1 + (quad ^ fk) * 8);
      short8v kf11 = *(const short8v*)(krow1 + ((4 + quad) ^ fk) * 8);
      __builtin_amdgcn_s_setprio(1);
      sa0 = __builtin_amdgcn_mfma_f32_16x16x32_bf16(kf00, qf0, sa0, 0, 0, 0);
      sa0 = __builtin_amdgcn_mfma_f32_16x16x32_bf16(kf01, qf1, sa0, 0, 0, 0);
      sa1 = __builtin_amdgcn_mfma_f32_16x16x32_bf16(kf10, qf0, sa1, 0, 0, 0);
      sa1 = __builtin_amdgcn_mfma_f32_16x16x32_bf16(kf11, qf1, sa1, 0, 0, 0);
      __builtin_amdgcn_s_setprio(0);
      // lane (quad,l=ln15): sa0[r] = score'[s=32U+8q+r][l], sa1[r] = +4
      // where score' = score * log2(e)

      float ps[8], pd[8];
      #pragma unroll
      for (int r = 0; r < 4; ++r) {
        float s0 = sa0[r], s1 = sa1[r];
        float r0 = s0 > 0.0f ? s0 : 0.0f;
        float r1 = s1 > 0.0f ? s1 : 0.0f;
        ps[r] = r0 * r0;  ps[4 + r] = r1 * r1;   // = (log2e)^2 * relu(s)^2
        pd[r] = fexp2(s0); pd[4 + r] = fexp2(s1); // = exp(s)
      }
      unsigned da[4] = { cvtpk(ps[0], ps[1]), cvtpk(ps[2], ps[3]),
                         cvtpk(ps[4], ps[5]), cvtpk(ps[6], ps[7]) };
      unsigned db[4] = { cvtpk(pd[0], pd[1]), cvtpk(pd[2], pd[3]),
                         cvtpk(pd[4], pd[5]), cvtpk(pd[6], pd[7]) };
      short8v as8 = *(const short8v*)da;   // A[m=l][k=s-32U] for K=32 PV
      short8v ad8 = *(const short8v*)db;

      __builtin_amdgcn_s_setprio(1);
      // denominator on the matrix pipe: acc_l[r] += sum_s pd[row=quad*4+r][s]
      acc_l = __builtin_amdgcn_mfma_f32_16x16x32_bf16(ad8, ones8, acc_l, 0, 0, 0);

      #pragma unroll
      for (int t = 0; t < 4; ++t) {
        short8v vf = *(const short8v*)(&vb_l[(t * 16 + ln15) * 64 +
                        (((4 * U + quad) ^ ln7) * 8)]);
        acc_s[t] = __builtin_amdgcn_mfma_f32_16x16x32_bf16(as8, vf, acc_s[t], 0, 0, 0);
        acc_d[t] = __builtin_amdgcn_mfma_f32_16x16x32_bf16(ad8, vf, acc_d[t], 0, 0, 0);
      }
      __builtin_amdgcn_s_setprio(0);
    }
  }

  // ---- combine the two s-streams (column-major scalar LDS, conflict-free) --
  __syncthreads();   // everyone done reading the last tiles -> ldsb reusable
  float* red = (float*)&ldsb[0][0][0];
  const int idx = ws * 64 + lane;        // same for partner waves strm 0/1
  if (strm == 1) {
    #pragma unroll
    for (int t = 0; t < 4; ++t)
      #pragma unroll
      for (int r = 0; r < 4; ++r) {
        red[(t * 4 + r) * 256 + idx]        = acc_s[t][r];
        red[(16 + t * 4 + r) * 256 + idx]   = acc_d[t][r];
      }
    #pragma unroll
    for (int r = 0; r < 4; ++r)
      red[(32 + r) * 256 + idx] = acc_l[r];
  }
  __syncthreads();
  if (strm == 0) {
    #pragma unroll
    for (int t = 0; t < 4; ++t)
      #pragma unroll
      for (int r = 0; r < 4; ++r) {
        acc_s[t][r] += red[(t * 4 + r) * 256 + idx];
        acc_d[t][r] += red[(16 + t * 4 + r) * 256 + idx];
      }
    #pragma unroll
    for (int r = 0; r < 4; ++r)
      acc_l[r] += red[(32 + r) * 256 + idx];

    const float w1 = __expf(a1p[0]), w2 = __expf(a2p[0]);
    // fold the (log2 e)^2 from the pre-scaled scores out of the sparse branch
    const float al1 = (w1 / (w1 + w2)) * 0.48045301391820142f; // (ln 2)^2
    const float al2 = w2 / (w1 + w2);

    float c_d[4];
    #pragma unroll
    for (int r = 0; r < 4; ++r) c_d[r] = al2 / acc_l[r];

    #pragma unroll
    for (int t = 0; t < 4; ++t) {
      #pragma unroll
      for (int r = 0; r < 4; ++r) {
        float val = al1 * acc_s[t][r] + c_d[r] * acc_d[t][r];
        const int l = lbase + quad * 4 + r;
        const int e = t * 16 + ln15;
        op[((size_t)(b * NL + l)) * HE + h * NE + e] = val;
      }
    }
  }
}

extern "C" void kernel_launch(void* const* d_in, const int* in_sizes, int n_in,
                              void* d_out, int out_size, void* d_ws, size_t ws_size,
                              hipStream_t stream) {
  const float* q  = (const float*)d_in[0];
  const float* k  = (const float*)d_in[1];
  const float* v  = (const float*)d_in[2];
  const float* a1 = (const float*)d_in[3];
  const float* a2 = (const float*)d_in[4];
  float* out = (float*)d_out;
  (void)in_sizes; (void)n_in; (void)out_size; (void)ws_size;

  u16* kimg = (u16*)d_ws;                                   // 4 MiB
  u16* vimg = kimg + (size_t)NB * NH * NST * TILE_U16;      // 4 MiB

  prepack<<<dim3(NB * NH * NST * 2), dim3(256), 0, stream>>>(k, v, kimg, vimg);
  assa_fwd<<<dim3(NB * NH * NLT), dim3(512), 0, stream>>>(q, kimg, vimg, a1, a2, out);
}